// Round 10
// baseline (296.317 us; speedup 1.0000x reference)
//
#include <hip/hip_runtime.h>
#include <stdint.h>

using u16 = unsigned short;
using short8 = __attribute__((ext_vector_type(8))) short;
using ushort8 = __attribute__((ext_vector_type(8))) unsigned short;
using f32x4  = __attribute__((ext_vector_type(4))) float;
using u32x4  = __attribute__((ext_vector_type(4))) unsigned int;

__device__ __forceinline__ float bf2f(u16 u) {
  return __builtin_bit_cast(float, ((unsigned)u) << 16);
}
__device__ __forceinline__ u16 f2bf(float f) {
  unsigned u = __builtin_bit_cast(unsigned, f);
  u += 0x7FFFu + ((u >> 16) & 1u);   // RNE
  return (u16)(u >> 16);
}
// BN+ReLU on a packed pair of bf16 (used by the fused gemm2 staging path)
__device__ __forceinline__ unsigned bn2(unsigned w, float a0, float s0, float a1, float s1) {
  float f0 = bf2f((u16)(w & 0xFFFFu)) * a0 + s0;
  float f1 = bf2f((u16)(w >> 16))     * a1 + s1;
  f0 = f0 > 0.0f ? f0 : 0.0f;
  f1 = f1 > 0.0f ? f1 : 0.0f;
  return (unsigned)f2bf(f0) | ((unsigned)f2bf(f1) << 16);
}

// branchless insert of (d,s) into sorted top-3; strict < keeps earlier entries on ties
__device__ __forceinline__ void ins3(float& d0, float& d1, float& d2,
                                     int& i0, int& i1, int& i2, float d, int s) {
  bool c0 = d < d0, c1 = d < d1, c2 = d < d2;
  d2 = c1 ? d1 : (c2 ? d : d2);
  i2 = c1 ? i1 : (c2 ? s : i2);
  d1 = c0 ? d0 : (c1 ? d : d1);
  i1 = c0 ? i0 : (c1 ? s : i1);
  d0 = c0 ? d : d0;
  i0 = c0 ? s : i0;
}

// ---------------- 3-NN + inverse-distance weights (fp32 in) ----------------
// grid (N/64, B), block 256. 8 threads per query; each thread scans its
// 128-candidate region for TWO queries (n, n+32) -> each ds_read_b128 is
// amortized over 2 queries (LDS pipe was the binding constraint: 1.05M wave
// b128 reads = ~20us; now halved). Partial top-3s merged via shfl_xor
// (lanes 8q..8q+7 in the same wave), per-query logic unchanged.
// LDS: 8 staggered regions, stride 516 floats -> conflict-free b128 reads.
// Scan metric d' = |c|^2 - 2*p.c (per-query constant r1 folded out).
__global__ __launch_bounds__(256, 8) void nn3_kernel(
    const float* __restrict__ xyz1, const float* __restrict__ xyz2,
    int* __restrict__ idx_out, float* __restrict__ w_out) {
  __shared__ __align__(16) float cand[8 * 516];  // 16512 B
  const int b = blockIdx.y;
  const int t = threadIdx.x;
  const float* x2 = xyz2 + b * 3072;
  for (int i = t; i < 1024; i += 256) {
    float x = x2[i], y = x2[1024 + i], z = x2[2048 + i];
    f32x4 v = { -2.0f * x, -2.0f * y, -2.0f * z, x*x + y*y + z*z };
    *(f32x4*)&cand[(i >> 7) * 516 + (i & 127) * 4] = v;
  }
  __syncthreads();
  const int q = t >> 3, sub = t & 7;
  const int nA = blockIdx.x * 64 + q;      // query A
  const int nB = nA + 32;                  // query B
  const float* x1 = xyz1 + b * 12288;
  const float pxA = x1[nA], pyA = x1[4096 + nA], pzA = x1[8192 + nA];
  const float pxB = x1[nB], pyB = x1[4096 + nB], pzB = x1[8192 + nB];
  float dA0 = 1e30f, dA1 = 1e30f, dA2 = 1e30f;
  float dB0 = 1e30f, dB1 = 1e30f, dB2 = 1e30f;
  int iA0 = 0, iA1 = 0, iA2 = 0, iB0 = 0, iB1 = 0, iB2 = 0;
  const int sbeg = sub << 7;
  const float* reg = &cand[sub * 516];
  #pragma unroll 2
  for (int ii = 0; ii < 128; ++ii) {
    f32x4 c = *(const f32x4*)(reg + ii * 4);
    float dA = __builtin_fmaf(pxA, c[0],
               __builtin_fmaf(pyA, c[1],
               __builtin_fmaf(pzA, c[2], c[3])));
    float dB = __builtin_fmaf(pxB, c[0],
               __builtin_fmaf(pyB, c[1],
               __builtin_fmaf(pzB, c[2], c[3])));
    ins3(dA0, dA1, dA2, iA0, iA1, iA2, dA, sbeg + ii);
    ins3(dB0, dB1, dB2, iB0, iB1, iB2, dB, sbeg + ii);
  }
  // merge 8 partial lists per query, butterfly; a-list is always the
  // lower-index range on sub==0's tree -> ties keep earlier scan index.
  for (int st = 1; st <= 4; st <<= 1) {
    float e0 = __shfl_xor(dA0, st), e1 = __shfl_xor(dA1, st), e2 = __shfl_xor(dA2, st);
    int   j0 = __shfl_xor(iA0, st), j1 = __shfl_xor(iA1, st), j2 = __shfl_xor(iA2, st);
    ins3(dA0, dA1, dA2, iA0, iA1, iA2, e0, j0);
    ins3(dA0, dA1, dA2, iA0, iA1, iA2, e1, j1);
    ins3(dA0, dA1, dA2, iA0, iA1, iA2, e2, j2);
    float g0 = __shfl_xor(dB0, st), g1 = __shfl_xor(dB1, st), g2 = __shfl_xor(dB2, st);
    int   k0 = __shfl_xor(iB0, st), k1 = __shfl_xor(iB1, st), k2 = __shfl_xor(iB2, st);
    ins3(dB0, dB1, dB2, iB0, iB1, iB2, g0, k0);
    ins3(dB0, dB1, dB2, iB0, iB1, iB2, g1, k1);
    ins3(dB0, dB1, dB2, iB0, iB1, iB2, g2, k2);
  }
  if (sub == 0) {
    {
      const float r1 = pxA*pxA + pyA*pyA + pzA*pzA;
      float w0 = 1.0f/(dA0 + r1 + 1e-8f), w1 = 1.0f/(dA1 + r1 + 1e-8f), w2 = 1.0f/(dA2 + r1 + 1e-8f);
      float inv = 1.0f/(w0 + w1 + w2);
      const int pos = b * 4096 + nA;
      idx_out[pos*3+0] = iA0; idx_out[pos*3+1] = iA1; idx_out[pos*3+2] = iA2;
      w_out[pos*3+0] = w0*inv; w_out[pos*3+1] = w1*inv; w_out[pos*3+2] = w2*inv;
    }
    {
      const float r1 = pxB*pxB + pyB*pyB + pzB*pzB;
      float w0 = 1.0f/(dB0 + r1 + 1e-8f), w1 = 1.0f/(dB1 + r1 + 1e-8f), w2 = 1.0f/(dB2 + r1 + 1e-8f);
      float inv = 1.0f/(w0 + w1 + w2);
      const int pos = b * 4096 + nB;
      idx_out[pos*3+0] = iB0; idx_out[pos*3+1] = iB1; idx_out[pos*3+2] = iB2;
      w_out[pos*3+0] = w0*inv; w_out[pos*3+1] = w1*inv; w_out[pos*3+2] = w2*inv;
    }
  }
}

// ---------------- [C=256][L] fp32 -> [L][C] bf16 transpose ----------------
// grid (L/64, 256/64, B), block 256. Write side: ushort2/lane (256 B/wave).
__global__ __launch_bounds__(256) void transpose_cl(
    const float* __restrict__ in, u16* __restrict__ out, int L, int rstride) {
  __shared__ u16 tile[64][66];
  const int b = blockIdx.z;
  in  += (size_t)b * 256 * L;
  out += (size_t)b * L * rstride;
  const int n0 = blockIdx.x * 64, c0 = blockIdx.y * 64;
  const int t = threadIdx.x, ln = t & 63, grp = t >> 6;
  for (int p = 0; p < 16; ++p) {
    int cc = p*4 + grp;
    tile[cc][ln] = f2bf(in[(size_t)(c0 + cc) * L + n0 + ln]);
  }
  __syncthreads();
  const int ln2 = t & 31, grp2 = t >> 5;      // 32 channel-pairs x 8 n-rows/iter
  for (int p = 0; p < 8; ++p) {
    int nn = p*8 + grp2;
    ushort2 v;
    v.x = tile[ln2*2][nn];
    v.y = tile[ln2*2 + 1][nn];
    *(ushort2*)&out[(size_t)(n0 + nn) * rstride + c0 + ln2*2] = v;
  }
}

// ---------------- fp32 -> bf16 weight conversion ----------------
__global__ __launch_bounds__(256) void cvt_kernel(const float* __restrict__ in,
                                                  u16* __restrict__ out, int n) {
  int i = blockIdx.x * 256 + threadIdx.x;
  if (i < n) out[i] = f2bf(in[i]);
}

// ---------------- 3-NN feature interpolation into A1 cols 256..511 ----------------
// grid 1024, block 256: 8 lane-groups of 32, each group does one position with
// ushort8 (16B) gathers; 8 iterations -> 64 positions per block.
__global__ __launch_bounds__(256) void interp_kernel(
    const u16* __restrict__ p2t, const int* __restrict__ idx,
    const float* __restrict__ wgt, u16* __restrict__ A1) {
  const int t = threadIdx.x;
  const int ln = t & 31, grp = t >> 5;
  const int c0 = ln * 8;
  for (int i = 0; i < 8; ++i) {
    const int pos = blockIdx.x * 64 + i * 8 + grp;
    const int b = pos >> 12;
    const int j0 = idx[pos*3+0], j1 = idx[pos*3+1], j2 = idx[pos*3+2];
    const float w0 = wgt[pos*3+0], w1 = wgt[pos*3+1], w2 = wgt[pos*3+2];
    ushort8 v0 = *(const ushort8*)(p2t + ((size_t)(b*1024 + j0)) * 256 + c0);
    ushort8 v1 = *(const ushort8*)(p2t + ((size_t)(b*1024 + j1)) * 256 + c0);
    ushort8 v2 = *(const ushort8*)(p2t + ((size_t)(b*1024 + j2)) * 256 + c0);
    ushort8 o;
    #pragma unroll
    for (int j = 0; j < 8; ++j)
      o[j] = f2bf(w0*bf2f(v0[j]) + w1*bf2f(v1[j]) + w2*bf2f(v2[j]));
    *(ushort8*)(A1 + (size_t)pos*512 + 256 + c0) = o;
  }
}

// ---------------- bf16 GEMM + fused per-channel stats (+optional fused BN) ----
// Y[m][n] = sum_k Ain[m][k]*Bw[n][k] + bias[n], where Ain = A (FUSE=0) or
// Ain = relu(A*bn_scale[k]+bn_shift[k]) applied during staging (FUSE=1, bit-
// identical to the old standalone bnrelu kernel's bf16 output).
// grid (M/128, N/128), block 256 (4 waves, 2x2 of 64x64 per wave).
// K-loop: round-1 compiler-scheduled structure (reg-staged, 2 barriers/step;
// manual pipelines all regressed r3-r5), BK=64 (r8: 46->41 us).
// LDS row stride 72 u16 = 144 B: uniform 8 lanes/16B window on both sides.
// Stats: wave shfl-reduce -> LDS atomic (dead As reuse) -> one global atomic
// per col per block into 8-way banked sums[8][256] (r6/r7 contention lesson).
template <int FUSE>
__global__ __launch_bounds__(256) void gemm_kernel(
    const u16* __restrict__ A, const u16* __restrict__ Bw,
    const float* __restrict__ bias, u16* __restrict__ Y, int K,
    float* __restrict__ sums, float* __restrict__ sumsq,
    const float* __restrict__ bn_scale, const float* __restrict__ bn_shift) {
  __shared__ __align__(16) u16 As[128*72];
  __shared__ __align__(16) u16 Bs[128*72];
  const int t = threadIdx.x;
  const int m0 = blockIdx.x * 128, n0 = blockIdx.y * 128;
  const int wave = t >> 6, l = t & 63;
  const int wm = wave & 1, wn = wave >> 1;
  const int lc = l & 15, quad = l >> 4;
  f32x4 acc[4][4] = {};
  const int r = t >> 3, kc = (t & 7) * 8;   // staging: 8 threads/row, 16B each
  for (int k0 = 0; k0 < K; k0 += 64) {
    f32x4 sc_lo, sc_hi, sh_lo, sh_hi;
    if (FUSE) {
      sc_lo = *(const f32x4*)&bn_scale[k0 + kc];
      sc_hi = *(const f32x4*)&bn_scale[k0 + kc + 4];
      sh_lo = *(const f32x4*)&bn_shift[k0 + kc];
      sh_hi = *(const f32x4*)&bn_shift[k0 + kc + 4];
    }
    #pragma unroll
    for (int p = 0; p < 4; ++p) {
      const int row = p*32 + r;
      u32x4 va = *(const u32x4*)&A [(size_t)(m0 + row)*K + k0 + kc];
      u32x4 vb = *(const u32x4*)&Bw[(size_t)(n0 + row)*K + k0 + kc];
      if (FUSE) {
        va[0] = bn2(va[0], sc_lo[0], sh_lo[0], sc_lo[1], sh_lo[1]);
        va[1] = bn2(va[1], sc_lo[2], sh_lo[2], sc_lo[3], sh_lo[3]);
        va[2] = bn2(va[2], sc_hi[0], sh_hi[0], sc_hi[1], sh_hi[1]);
        va[3] = bn2(va[3], sc_hi[2], sh_hi[2], sc_hi[3], sh_hi[3]);
      }
      *(u32x4*)&As[row*72 + kc] = va;
      *(u32x4*)&Bs[row*72 + kc] = vb;
    }
    __syncthreads();
    #pragma unroll
    for (int h = 0; h < 2; ++h) {
      short8 af[4], bfv[4];
      for (int tm = 0; tm < 4; ++tm)
        af[tm] = *(const short8*)&As[(wm*64 + tm*16 + lc)*72 + h*32 + quad*8];
      for (int tn = 0; tn < 4; ++tn)
        bfv[tn] = *(const short8*)&Bs[(wn*64 + tn*16 + lc)*72 + h*32 + quad*8];
      for (int tm = 0; tm < 4; ++tm)
        for (int tn = 0; tn < 4; ++tn)
          acc[tm][tn] = __builtin_amdgcn_mfma_f32_16x16x32_bf16(af[tm], bfv[tn], acc[tm][tn], 0, 0, 0);
    }
    __syncthreads();
  }
  // As is dead now -> reuse 1 KiB as the block's stats scratch.
  float* sl = (float*)As;            // sl[0..127]=sum per block-col, sl[128..255]=sumsq
  if (t < 256) sl[t] = 0.0f;
  __syncthreads();
  for (int tn = 0; tn < 4; ++tn) {
    const int colL = wn*64 + tn*16 + lc;          // col within block [0,128)
    const float bb = bias[n0 + colL];
    float s = 0.0f, q = 0.0f;
    for (int tm = 0; tm < 4; ++tm) {
      const int row = m0 + wm*64 + tm*16 + quad*4;
      for (int rr = 0; rr < 4; ++rr) {
        float v = acc[tm][tn][rr] + bb;           // C/D: col=lane&15, row=quad*4+reg
        Y[(size_t)(row + rr)*256 + n0 + colL] = f2bf(v);
        s += v; q += v*v;
      }
    }
    // reduce the 4 quads holding this col, then LDS-atomic (2 waves/addr)
    s += __shfl_xor(s, 16); s += __shfl_xor(s, 32);
    q += __shfl_xor(q, 16); q += __shfl_xor(q, 32);
    if (quad == 0) {
      atomicAdd(&sl[colL], s);
      atomicAdd(&sl[128 + colL], q);
    }
  }
  __syncthreads();
  if (t < 128) {                     // one global atomic per col per block, 8-banked
    const int bank = (blockIdx.x & 7) * 256;
    atomicAdd(&sums [bank + n0 + t], sl[t]);
    atomicAdd(&sumsq[bank + n0 + t], sl[128 + t]);
  }
}

// sums/sumsq are [8][256] banks; reduce banks here.
__global__ void bnprep_kernel(const float* __restrict__ sums, const float* __restrict__ sumsq,
                              const float* __restrict__ g, const float* __restrict__ be,
                              float* __restrict__ scale, float* __restrict__ shift) {
  const int t = threadIdx.x;
  float s = 0.0f, q = 0.0f;
  for (int k = 0; k < 8; ++k) { s += sums[k*256 + t]; q += sumsq[k*256 + t]; }
  const float inv_n = 1.0f / 65536.0f;
  float mean = s * inv_n;
  float var = q * inv_n - mean*mean;  // biased var, matches jnp.var
  float a = g[t] * rsqrtf(var + 1e-5f);
  scale[t] = a;
  shift[t] = be[t] - mean * a;
}

// ---------------- BN+ReLU + transpose to [b][c][n] fp32 output ----------------
// grid (64, 1, 16), block 256. Vectorized: ushort4 channel-quad reads (16
// instead of 64 global loads), ds_write_b64 into [n][c] tile (stride 266:
// 133*ln mod 32 coprime -> conflict-free u32 reads in phase 2).
__global__ __launch_bounds__(256) void bnrelu_tr_kernel(
    const u16* __restrict__ Y, const float* __restrict__ scale,
    const float* __restrict__ shift, float* __restrict__ out) {
  __shared__ u16 tile[64][266];   // [n - n0][channel]
  const int t = threadIdx.x;
  const int b = blockIdx.z;
  const int n0 = blockIdx.x * 64;
  const int ln = t & 63, grp = t >> 6;
  const int c0 = ln * 4;
  const f32x4 a4 = *(const f32x4*)&scale[c0];
  const f32x4 s4 = *(const f32x4*)&shift[c0];
  for (int it = 0; it < 16; ++it) {
    const int nn = it*4 + grp;
    size_t pos = (size_t)b*4096 + n0 + nn;
    ushort4 v = *(const ushort4*)&Y[pos*256 + c0];
    ushort4 o;
    float f0 = bf2f(v.x)*a4[0] + s4[0];
    float f1 = bf2f(v.y)*a4[1] + s4[1];
    float f2v = bf2f(v.z)*a4[2] + s4[2];
    float f3 = bf2f(v.w)*a4[3] + s4[3];
    o.x = f2bf(f0 > 0.0f ? f0 : 0.0f);
    o.y = f2bf(f1 > 0.0f ? f1 : 0.0f);
    o.z = f2bf(f2v > 0.0f ? f2v : 0.0f);
    o.w = f2bf(f3 > 0.0f ? f3 : 0.0f);
    *(ushort4*)&tile[nn][c0] = o;   // ds_write_b64
  }
  __syncthreads();
  // phase 2: lane = n index; each iteration covers 2 channels via one u32 read
  for (int p = 0; p < 32; ++p) {
    const int oo = p*8 + grp*2;
    ushort2 v = *(const ushort2*)&tile[ln][oo];   // u32 LDS read, conflict-free
    out[((size_t)b*256 + oo    )*4096 + n0 + ln] = bf2f(v.x);
    out[((size_t)b*256 + oo + 1)*4096 + n0 + ln] = bf2f(v.y);
  }
}

extern "C" void kernel_launch(void* const* d_in, const int* in_sizes, int n_in,
                              void* d_out, int out_size, void* d_ws, size_t ws_size,
                              hipStream_t stream) {
  const float* xyz1    = (const float*)d_in[0];
  const float* xyz2    = (const float*)d_in[1];
  const float* points1 = (const float*)d_in[2];
  const float* points2 = (const float*)d_in[3];
  const float* w0      = (const float*)d_in[4];
  const float* b0      = (const float*)d_in[5];
  const float* g0      = (const float*)d_in[6];
  const float* be0     = (const float*)d_in[7];
  const float* w1      = (const float*)d_in[8];
  const float* b1      = (const float*)d_in[9];
  const float* g1      = (const float*)d_in[10];
  const float* be1     = (const float*)d_in[11];
  float* out = (float*)d_out;

  // ---- workspace layout (~107 MiB used) ----
  char* ws = (char*)d_ws;
  u16*   A1   = (u16*)ws;                          // [65536][512] bf16, 64 MiB (dead after gemm1)
  u16*   Y2   = (u16*)ws;                          // [65536][256] bf16, 32 MiB (overlays dead A1)
  u16*   Y    = (u16*)(ws + (64ull  << 20));       // [65536][256] bf16, 32 MiB
  u16*   p2t  = (u16*)(ws + (96ull  << 20));       // [16*1024][256] bf16, 8 MiB
  int*   idxb = (int*)(ws + (104ull << 20));       // 768 KiB
  float* wgtb = (float*)(ws + (105ull << 20));     // 768 KiB
  u16*   w0b  = (u16*)(ws + (106ull << 20));       // [256][512] bf16, 256 KiB
  u16*   w1b  = (u16*)(ws + (106ull << 20) + (256u << 10)); // [256][256] bf16, 128 KiB
  float* stats= (float*)(ws + (106ull << 20) + (512u << 10)); // 9216 floats

  // banked accumulators [8][256] each, then scale/shift
  float* sums0  = stats;          // 2048
  float* sumsq0 = stats + 2048;   // 2048
  float* sums1  = stats + 4096;   // 2048
  float* sumsq1 = stats + 6144;   // 2048
  float* scale0 = stats + 8192, *shift0 = stats + 8448;
  float* scale1 = stats + 8704, *shift1 = stats + 8960;

  hipMemsetAsync(stats, 0, 8192 * sizeof(float), stream);
  nn3_kernel<<<dim3(64, 16), 256, 0, stream>>>(xyz1, xyz2, idxb, wgtb);
  transpose_cl<<<dim3(16, 4, 16), 256, 0, stream>>>(points2, p2t, 1024, 256);
  transpose_cl<<<dim3(64, 4, 16), 256, 0, stream>>>(points1, A1, 4096, 512);
  cvt_kernel<<<512, 256, 0, stream>>>(w0, w0b, 131072);
  cvt_kernel<<<256, 256, 0, stream>>>(w1, w1b, 65536);
  interp_kernel<<<1024, 256, 0, stream>>>(p2t, idxb, wgtb, A1);
  gemm_kernel<0><<<dim3(512, 2), 256, 0, stream>>>(A1, w0b, b0, Y, 512, sums0, sumsq0, nullptr, nullptr);
  bnprep_kernel<<<1, 256, 0, stream>>>(sums0, sumsq0, g0, be0, scale0, shift0);
  gemm_kernel<1><<<dim3(512, 2), 256, 0, stream>>>(Y, w1b, b1, Y2, 256, sums1, sumsq1, scale0, shift0);
  bnprep_kernel<<<1, 256, 0, stream>>>(sums1, sumsq1, g1, be1, scale1, shift1);
  bnrelu_tr_kernel<<<dim3(64, 1, 16), 256, 0, stream>>>(Y2, scale1, shift1, out);
}

// Round 11
// 290.750 us; speedup vs baseline: 1.0191x; 1.0191x over previous
//
#include <hip/hip_runtime.h>
#include <stdint.h>

using u16 = unsigned short;
using short8 = __attribute__((ext_vector_type(8))) short;
using ushort8 = __attribute__((ext_vector_type(8))) unsigned short;
using f32x4  = __attribute__((ext_vector_type(4))) float;
using u32x4  = __attribute__((ext_vector_type(4))) unsigned int;

__device__ __forceinline__ float bf2f(u16 u) {
  return __builtin_bit_cast(float, ((unsigned)u) << 16);
}
__device__ __forceinline__ u16 f2bf(float f) {
  unsigned u = __builtin_bit_cast(unsigned, f);
  u += 0x7FFFu + ((u >> 16) & 1u);   // RNE
  return (u16)(u >> 16);
}
// BN+ReLU on a packed pair of bf16 (used by the fused gemm2 staging path)
__device__ __forceinline__ unsigned bn2(unsigned w, float a0, float s0, float a1, float s1) {
  float f0 = bf2f((u16)(w & 0xFFFFu)) * a0 + s0;
  float f1 = bf2f((u16)(w >> 16))     * a1 + s1;
  f0 = f0 > 0.0f ? f0 : 0.0f;
  f1 = f1 > 0.0f ? f1 : 0.0f;
  return (unsigned)f2bf(f0) | ((unsigned)f2bf(f1) << 16);
}
// per-channel BN scale/shift from banked sums (identical math to old bnprep;
// recomputed redundantly per block -> kills the 1-block bnprep launches)
__device__ __forceinline__ void bnprep_to_lds(
    const float* __restrict__ in_sums, const float* __restrict__ in_sumsq,
    const float* __restrict__ g, const float* __restrict__ be,
    float* sc_s, float* sh_s, int t) {
  if (t < 256) {
    float s = 0.0f, q = 0.0f;
    for (int k = 0; k < 8; ++k) { s += in_sums[k*256 + t]; q += in_sumsq[k*256 + t]; }
    const float inv_n = 1.0f / 65536.0f;
    float mean = s * inv_n;
    float var = q * inv_n - mean*mean;  // biased var, matches jnp.var
    float a = g[t] * rsqrtf(var + 1e-5f);
    sc_s[t] = a;
    sh_s[t] = be[t] - mean * a;
  }
}

// branchless insert of (d,s) into sorted top-3; strict < keeps earlier entries on ties
__device__ __forceinline__ void ins3(float& d0, float& d1, float& d2,
                                     int& i0, int& i1, int& i2, float d, int s) {
  bool c0 = d < d0, c1 = d < d1, c2 = d < d2;
  d2 = c1 ? d1 : (c2 ? d : d2);
  i2 = c1 ? i1 : (c2 ? s : i2);
  d1 = c0 ? d0 : (c1 ? d : d1);
  i1 = c0 ? i0 : (c1 ? s : i1);
  d0 = c0 ? d : d0;
  i0 = c0 ? s : i0;
}

// ---------------- 3-NN + inverse-distance weights (fp32 in) ----------------
// grid (N/64, B), block 256. 8 threads per query; each thread scans its
// 128-candidate region for TWO queries (n, n+32) -> each ds_read_b128 is
// amortized over 2 queries (LDS pipe was the binding constraint).
// LDS: 8 staggered regions, stride 516 floats -> conflict-free b128 reads.
// Scan metric d' = |c|^2 - 2*p.c (per-query constant r1 folded out).
__global__ __launch_bounds__(256, 8) void nn3_kernel(
    const float* __restrict__ xyz1, const float* __restrict__ xyz2,
    int* __restrict__ idx_out, float* __restrict__ w_out) {
  __shared__ __align__(16) float cand[8 * 516];  // 16512 B
  const int b = blockIdx.y;
  const int t = threadIdx.x;
  const float* x2 = xyz2 + b * 3072;
  for (int i = t; i < 1024; i += 256) {
    float x = x2[i], y = x2[1024 + i], z = x2[2048 + i];
    f32x4 v = { -2.0f * x, -2.0f * y, -2.0f * z, x*x + y*y + z*z };
    *(f32x4*)&cand[(i >> 7) * 516 + (i & 127) * 4] = v;
  }
  __syncthreads();
  const int q = t >> 3, sub = t & 7;
  const int nA = blockIdx.x * 64 + q;      // query A
  const int nB = nA + 32;                  // query B
  const float* x1 = xyz1 + b * 12288;
  const float pxA = x1[nA], pyA = x1[4096 + nA], pzA = x1[8192 + nA];
  const float pxB = x1[nB], pyB = x1[4096 + nB], pzB = x1[8192 + nB];
  float dA0 = 1e30f, dA1 = 1e30f, dA2 = 1e30f;
  float dB0 = 1e30f, dB1 = 1e30f, dB2 = 1e30f;
  int iA0 = 0, iA1 = 0, iA2 = 0, iB0 = 0, iB1 = 0, iB2 = 0;
  const int sbeg = sub << 7;
  const float* reg = &cand[sub * 516];
  #pragma unroll 2
  for (int ii = 0; ii < 128; ++ii) {
    f32x4 c = *(const f32x4*)(reg + ii * 4);
    float dA = __builtin_fmaf(pxA, c[0],
               __builtin_fmaf(pyA, c[1],
               __builtin_fmaf(pzA, c[2], c[3])));
    float dB = __builtin_fmaf(pxB, c[0],
               __builtin_fmaf(pyB, c[1],
               __builtin_fmaf(pzB, c[2], c[3])));
    ins3(dA0, dA1, dA2, iA0, iA1, iA2, dA, sbeg + ii);
    ins3(dB0, dB1, dB2, iB0, iB1, iB2, dB, sbeg + ii);
  }
  // merge 8 partial lists per query, butterfly; a-list is always the
  // lower-index range on sub==0's tree -> ties keep earlier scan index.
  for (int st = 1; st <= 4; st <<= 1) {
    float e0 = __shfl_xor(dA0, st), e1 = __shfl_xor(dA1, st), e2 = __shfl_xor(dA2, st);
    int   j0 = __shfl_xor(iA0, st), j1 = __shfl_xor(iA1, st), j2 = __shfl_xor(iA2, st);
    ins3(dA0, dA1, dA2, iA0, iA1, iA2, e0, j0);
    ins3(dA0, dA1, dA2, iA0, iA1, iA2, e1, j1);
    ins3(dA0, dA1, dA2, iA0, iA1, iA2, e2, j2);
    float g0 = __shfl_xor(dB0, st), g1 = __shfl_xor(dB1, st), g2 = __shfl_xor(dB2, st);
    int   k0 = __shfl_xor(iB0, st), k1 = __shfl_xor(iB1, st), k2 = __shfl_xor(iB2, st);
    ins3(dB0, dB1, dB2, iB0, iB1, iB2, g0, k0);
    ins3(dB0, dB1, dB2, iB0, iB1, iB2, g1, k1);
    ins3(dB0, dB1, dB2, iB0, iB1, iB2, g2, k2);
  }
  if (sub == 0) {
    {
      const float r1 = pxA*pxA + pyA*pyA + pzA*pzA;
      float w0 = 1.0f/(dA0 + r1 + 1e-8f), w1 = 1.0f/(dA1 + r1 + 1e-8f), w2 = 1.0f/(dA2 + r1 + 1e-8f);
      float inv = 1.0f/(w0 + w1 + w2);
      const int pos = b * 4096 + nA;
      idx_out[pos*3+0] = iA0; idx_out[pos*3+1] = iA1; idx_out[pos*3+2] = iA2;
      w_out[pos*3+0] = w0*inv; w_out[pos*3+1] = w1*inv; w_out[pos*3+2] = w2*inv;
    }
    {
      const float r1 = pxB*pxB + pyB*pyB + pzB*pzB;
      float w0 = 1.0f/(dB0 + r1 + 1e-8f), w1 = 1.0f/(dB1 + r1 + 1e-8f), w2 = 1.0f/(dB2 + r1 + 1e-8f);
      float inv = 1.0f/(w0 + w1 + w2);
      const int pos = b * 4096 + nB;
      idx_out[pos*3+0] = iB0; idx_out[pos*3+1] = iB1; idx_out[pos*3+2] = iB2;
      w_out[pos*3+0] = w0*inv; w_out[pos*3+1] = w1*inv; w_out[pos*3+2] = w2*inv;
    }
  }
}

// ---------------- merged [C=256][L] fp32 -> [L][C] bf16 transposes ----------------
// One launch for both tensors: grid (80, 4, 16), block 256.
// x<64: points1 (L=4096, rstride=512) -> A1; x in [64,80): points2 (L=1024,
// rstride=256) -> p2t. Config select is block-uniform (no divergence).
__global__ __launch_bounds__(256) void transpose2_cl(
    const float* __restrict__ in1, u16* __restrict__ out1,
    const float* __restrict__ in2, u16* __restrict__ out2) {
  __shared__ u16 tile[64][66];
  const int bx = blockIdx.x, b = blockIdx.z;
  const float* in; u16* out; int L, rstride, n0;
  if (bx < 64) { in = in1; out = out1; L = 4096; rstride = 512; n0 = bx * 64; }
  else         { in = in2; out = out2; L = 1024; rstride = 256; n0 = (bx - 64) * 64; }
  in  += (size_t)b * 256 * L;
  out += (size_t)b * L * rstride;
  const int c0 = blockIdx.y * 64;
  const int t = threadIdx.x, ln = t & 63, grp = t >> 6;
  for (int p = 0; p < 16; ++p) {
    int cc = p*4 + grp;
    tile[cc][ln] = f2bf(in[(size_t)(c0 + cc) * L + n0 + ln]);
  }
  __syncthreads();
  const int ln2 = t & 31, grp2 = t >> 5;      // 32 channel-pairs x 8 n-rows/iter
  for (int p = 0; p < 8; ++p) {
    int nn = p*8 + grp2;
    ushort2 v;
    v.x = tile[ln2*2][nn];
    v.y = tile[ln2*2 + 1][nn];
    *(ushort2*)&out[(size_t)(n0 + nn) * rstride + c0 + ln2*2] = v;
  }
}

// ---------------- fp32 -> bf16 conversion for both weight tensors ----------------
// grid 768: first 512 blocks convert w0 (131072), rest convert w1 (65536).
__global__ __launch_bounds__(256) void cvt2_kernel(
    const float* __restrict__ a, u16* __restrict__ oa, int na,
    const float* __restrict__ b2, u16* __restrict__ ob, int nb) {
  int i = blockIdx.x * 256 + threadIdx.x;
  if (i < na) { oa[i] = f2bf(a[i]); }
  else { int j = i - na; if (j < nb) ob[j] = f2bf(b2[j]); }
}

// ---------------- 3-NN feature interpolation into A1 cols 256..511 ----------------
// grid 1024, block 256: 8 lane-groups of 32, each group does one position with
// ushort8 (16B) gathers; 8 iterations -> 64 positions per block.
__global__ __launch_bounds__(256) void interp_kernel(
    const u16* __restrict__ p2t, const int* __restrict__ idx,
    const float* __restrict__ wgt, u16* __restrict__ A1) {
  const int t = threadIdx.x;
  const int ln = t & 31, grp = t >> 5;
  const int c0 = ln * 8;
  for (int i = 0; i < 8; ++i) {
    const int pos = blockIdx.x * 64 + i * 8 + grp;
    const int b = pos >> 12;
    const int j0 = idx[pos*3+0], j1 = idx[pos*3+1], j2 = idx[pos*3+2];
    const float w0 = wgt[pos*3+0], w1 = wgt[pos*3+1], w2 = wgt[pos*3+2];
    ushort8 v0 = *(const ushort8*)(p2t + ((size_t)(b*1024 + j0)) * 256 + c0);
    ushort8 v1 = *(const ushort8*)(p2t + ((size_t)(b*1024 + j1)) * 256 + c0);
    ushort8 v2 = *(const ushort8*)(p2t + ((size_t)(b*1024 + j2)) * 256 + c0);
    ushort8 o;
    #pragma unroll
    for (int j = 0; j < 8; ++j)
      o[j] = f2bf(w0*bf2f(v0[j]) + w1*bf2f(v1[j]) + w2*bf2f(v2[j]));
    *(ushort8*)(A1 + (size_t)pos*512 + 256 + c0) = o;
  }
}

// ---------------- bf16 GEMM + fused per-channel stats (+optional fused BN) ----
// Y[m][n] = sum_k Ain[m][k]*Bw[n][k] + bias[n], where Ain = A (FUSE=0) or
// Ain = relu(A*scale[k]+shift[k]) with scale/shift computed IN-KERNEL from the
// previous layer's banked sums (identical math to old bnprep; deterministic,
// so every block computes the same values -> no separate launch needed).
// grid (M/128, N/128), block 256 (4 waves, 2x2 of 64x64 per wave).
// K-loop: round-1 compiler-scheduled structure (reg-staged, 2 barriers/step;
// manual pipelines all regressed r3-r5), BK=64 (r8: 46->41 us).
// LDS row stride 72 u16 = 144 B: uniform 8 lanes/16B window on both sides.
// Stats out: wave shfl-reduce -> LDS atomic (dead As reuse) -> one global
// atomic per col per block into 8-way banked sums[8][256] (r6/r7 lesson).
template <int FUSE>
__global__ __launch_bounds__(256) void gemm_kernel(
    const u16* __restrict__ A, const u16* __restrict__ Bw,
    const float* __restrict__ bias, u16* __restrict__ Y, int K,
    float* __restrict__ sums, float* __restrict__ sumsq,
    const float* __restrict__ in_sums, const float* __restrict__ in_sumsq,
    const float* __restrict__ g, const float* __restrict__ be) {
  __shared__ __align__(16) u16 As[128*72];
  __shared__ __align__(16) u16 Bs[128*72];
  __shared__ float sc_s[256], sh_s[256];
  const int t = threadIdx.x;
  const int m0 = blockIdx.x * 128, n0 = blockIdx.y * 128;
  const int wave = t >> 6, l = t & 63;
  const int wm = wave & 1, wn = wave >> 1;
  const int lc = l & 15, quad = l >> 4;
  f32x4 acc[4][4] = {};
  const int r = t >> 3, kc = (t & 7) * 8;   // staging: 8 threads/row, 16B each
  if (FUSE) {
    bnprep_to_lds(in_sums, in_sumsq, g, be, sc_s, sh_s, t);
    __syncthreads();
  }
  for (int k0 = 0; k0 < K; k0 += 64) {
    f32x4 sc_lo, sc_hi, sh_lo, sh_hi;
    if (FUSE) {
      sc_lo = *(const f32x4*)&sc_s[k0 + kc];
      sc_hi = *(const f32x4*)&sc_s[k0 + kc + 4];
      sh_lo = *(const f32x4*)&sh_s[k0 + kc];
      sh_hi = *(const f32x4*)&sh_s[k0 + kc + 4];
    }
    #pragma unroll
    for (int p = 0; p < 4; ++p) {
      const int row = p*32 + r;
      u32x4 va = *(const u32x4*)&A [(size_t)(m0 + row)*K + k0 + kc];
      u32x4 vb = *(const u32x4*)&Bw[(size_t)(n0 + row)*K + k0 + kc];
      if (FUSE) {
        va[0] = bn2(va[0], sc_lo[0], sh_lo[0], sc_lo[1], sh_lo[1]);
        va[1] = bn2(va[1], sc_lo[2], sh_lo[2], sc_lo[3], sh_lo[3]);
        va[2] = bn2(va[2], sc_hi[0], sh_hi[0], sc_hi[1], sh_hi[1]);
        va[3] = bn2(va[3], sc_hi[2], sh_hi[2], sc_hi[3], sh_hi[3]);
      }
      *(u32x4*)&As[row*72 + kc] = va;
      *(u32x4*)&Bs[row*72 + kc] = vb;
    }
    __syncthreads();
    #pragma unroll
    for (int h = 0; h < 2; ++h) {
      short8 af[4], bfv[4];
      for (int tm = 0; tm < 4; ++tm)
        af[tm] = *(const short8*)&As[(wm*64 + tm*16 + lc)*72 + h*32 + quad*8];
      for (int tn = 0; tn < 4; ++tn)
        bfv[tn] = *(const short8*)&Bs[(wn*64 + tn*16 + lc)*72 + h*32 + quad*8];
      for (int tm = 0; tm < 4; ++tm)
        for (int tn = 0; tn < 4; ++tn)
          acc[tm][tn] = __builtin_amdgcn_mfma_f32_16x16x32_bf16(af[tm], bfv[tn], acc[tm][tn], 0, 0, 0);
    }
    __syncthreads();
  }
  // As is dead now -> reuse 1 KiB as the block's stats scratch.
  float* sl = (float*)As;            // sl[0..127]=sum per block-col, sl[128..255]=sumsq
  if (t < 256) sl[t] = 0.0f;
  __syncthreads();
  for (int tn = 0; tn < 4; ++tn) {
    const int colL = wn*64 + tn*16 + lc;          // col within block [0,128)
    const float bb = bias[n0 + colL];
    float s = 0.0f, q = 0.0f;
    for (int tm = 0; tm < 4; ++tm) {
      const int row = m0 + wm*64 + tm*16 + quad*4;
      for (int rr = 0; rr < 4; ++rr) {
        float v = acc[tm][tn][rr] + bb;           // C/D: col=lane&15, row=quad*4+reg
        Y[(size_t)(row + rr)*256 + n0 + colL] = f2bf(v);
        s += v; q += v*v;
      }
    }
    // reduce the 4 quads holding this col, then LDS-atomic (2 waves/addr)
    s += __shfl_xor(s, 16); s += __shfl_xor(s, 32);
    q += __shfl_xor(q, 16); q += __shfl_xor(q, 32);
    if (quad == 0) {
      atomicAdd(&sl[colL], s);
      atomicAdd(&sl[128 + colL], q);
    }
  }
  __syncthreads();
  if (t < 128) {                     // one global atomic per col per block, 8-banked
    const int bank = (blockIdx.x & 7) * 256;
    atomicAdd(&sums [bank + n0 + t], sl[t]);
    atomicAdd(&sumsq[bank + n0 + t], sl[128 + t]);
  }
}

// ---------------- BN+ReLU + transpose to [b][c][n] fp32 output ----------------
// grid (64, 1, 16), block 256. scale/shift computed in-kernel from banked sums
// (kills the second bnprep launch). Vectorized ushort4 reads; ds_write_b64
// into [n][c] tile (stride 266 -> conflict-free u32 reads in phase 2).
__global__ __launch_bounds__(256) void bnrelu_tr_kernel(
    const u16* __restrict__ Y,
    const float* __restrict__ in_sums, const float* __restrict__ in_sumsq,
    const float* __restrict__ g, const float* __restrict__ be,
    float* __restrict__ out) {
  __shared__ u16 tile[64][266];   // [n - n0][channel]
  __shared__ float sc_s[256], sh_s[256];
  const int t = threadIdx.x;
  const int b = blockIdx.z;
  const int n0 = blockIdx.x * 64;
  bnprep_to_lds(in_sums, in_sumsq, g, be, sc_s, sh_s, t);
  __syncthreads();
  const int ln = t & 63, grp = t >> 6;
  const int c0 = ln * 4;
  const f32x4 a4 = *(const f32x4*)&sc_s[c0];
  const f32x4 s4 = *(const f32x4*)&sh_s[c0];
  for (int it = 0; it < 16; ++it) {
    const int nn = it*4 + grp;
    size_t pos = (size_t)b*4096 + n0 + nn;
    ushort4 v = *(const ushort4*)&Y[pos*256 + c0];
    ushort4 o;
    float f0 = bf2f(v.x)*a4[0] + s4[0];
    float f1 = bf2f(v.y)*a4[1] + s4[1];
    float f2v = bf2f(v.z)*a4[2] + s4[2];
    float f3 = bf2f(v.w)*a4[3] + s4[3];
    o.x = f2bf(f0 > 0.0f ? f0 : 0.0f);
    o.y = f2bf(f1 > 0.0f ? f1 : 0.0f);
    o.z = f2bf(f2v > 0.0f ? f2v : 0.0f);
    o.w = f2bf(f3 > 0.0f ? f3 : 0.0f);
    *(ushort4*)&tile[nn][c0] = o;   // ds_write_b64
  }
  __syncthreads();
  // phase 2: lane = n index; each iteration covers 2 channels via one u32 read
  for (int p = 0; p < 32; ++p) {
    const int oo = p*8 + grp*2;
    ushort2 v = *(const ushort2*)&tile[ln][oo];   // u32 LDS read, conflict-free
    out[((size_t)b*256 + oo    )*4096 + n0 + ln] = bf2f(v.x);
    out[((size_t)b*256 + oo + 1)*4096 + n0 + ln] = bf2f(v.y);
  }
}

extern "C" void kernel_launch(void* const* d_in, const int* in_sizes, int n_in,
                              void* d_out, int out_size, void* d_ws, size_t ws_size,
                              hipStream_t stream) {
  const float* xyz1    = (const float*)d_in[0];
  const float* xyz2    = (const float*)d_in[1];
  const float* points1 = (const float*)d_in[2];
  const float* points2 = (const float*)d_in[3];
  const float* w0      = (const float*)d_in[4];
  const float* b0      = (const float*)d_in[5];
  const float* g0      = (const float*)d_in[6];
  const float* be0     = (const float*)d_in[7];
  const float* w1      = (const float*)d_in[8];
  const float* b1      = (const float*)d_in[9];
  const float* g1      = (const float*)d_in[10];
  const float* be1     = (const float*)d_in[11];
  float* out = (float*)d_out;

  // ---- workspace layout (~107 MiB used) ----
  char* ws = (char*)d_ws;
  u16*   A1   = (u16*)ws;                          // [65536][512] bf16, 64 MiB (dead after gemm1)
  u16*   Y2   = (u16*)ws;                          // [65536][256] bf16, 32 MiB (overlays dead A1)
  u16*   Y    = (u16*)(ws + (64ull  << 20));       // [65536][256] bf16, 32 MiB
  u16*   p2t  = (u16*)(ws + (96ull  << 20));       // [16*1024][256] bf16, 8 MiB
  int*   idxb = (int*)(ws + (104ull << 20));       // 768 KiB
  float* wgtb = (float*)(ws + (105ull << 20));     // 768 KiB
  u16*   w0b  = (u16*)(ws + (106ull << 20));       // [256][512] bf16, 256 KiB
  u16*   w1b  = (u16*)(ws + (106ull << 20) + (256u << 10)); // [256][256] bf16, 128 KiB
  float* stats= (float*)(ws + (106ull << 20) + (512u << 10)); // 8192 floats

  // banked accumulators [8][256] each
  float* sums0  = stats;          // 2048
  float* sumsq0 = stats + 2048;   // 2048
  float* sums1  = stats + 4096;   // 2048
  float* sumsq1 = stats + 6144;   // 2048

  hipMemsetAsync(stats, 0, 8192 * sizeof(float), stream);
  nn3_kernel<<<dim3(64, 16), 256, 0, stream>>>(xyz1, xyz2, idxb, wgtb);
  transpose2_cl<<<dim3(80, 4, 16), 256, 0, stream>>>(points1, A1, points2, p2t);
  cvt2_kernel<<<768, 256, 0, stream>>>(w0, w0b, 131072, w1, w1b, 65536);
  interp_kernel<<<1024, 256, 0, stream>>>(p2t, idxb, wgtb, A1);
  gemm_kernel<0><<<dim3(512, 2), 256, 0, stream>>>(A1, w0b, b0, Y, 512, sums0, sumsq0,
                                                   nullptr, nullptr, nullptr, nullptr);
  gemm_kernel<1><<<dim3(512, 2), 256, 0, stream>>>(Y, w1b, b1, Y2, 256, sums1, sumsq1,
                                                   sums0, sumsq0, g0, be0);
  bnrelu_tr_kernel<<<dim3(64, 1, 16), 256, 0, stream>>>(Y2, sums1, sumsq1, g1, be1, out);
}

// Round 12
// 288.804 us; speedup vs baseline: 1.0260x; 1.0067x over previous
//
#include <hip/hip_runtime.h>
#include <stdint.h>

using u16 = unsigned short;
using short8 = __attribute__((ext_vector_type(8))) short;
using ushort8 = __attribute__((ext_vector_type(8))) unsigned short;
using f32x4  = __attribute__((ext_vector_type(4))) float;
using u32x4  = __attribute__((ext_vector_type(4))) unsigned int;

__device__ __forceinline__ float bf2f(u16 u) {
  return __builtin_bit_cast(float, ((unsigned)u) << 16);
}
__device__ __forceinline__ u16 f2bf(float f) {
  unsigned u = __builtin_bit_cast(unsigned, f);
  u += 0x7FFFu + ((u >> 16) & 1u);   // RNE
  return (u16)(u >> 16);
}
// BN+ReLU on a packed pair of bf16 (used by the fused gemm2 staging path)
__device__ __forceinline__ unsigned bn2(unsigned w, float a0, float s0, float a1, float s1) {
  float f0 = bf2f((u16)(w & 0xFFFFu)) * a0 + s0;
  float f1 = bf2f((u16)(w >> 16))     * a1 + s1;
  f0 = f0 > 0.0f ? f0 : 0.0f;
  f1 = f1 > 0.0f ? f1 : 0.0f;
  return (unsigned)f2bf(f0) | ((unsigned)f2bf(f1) << 16);
}
// per-channel BN scale/shift from banked sums (identical math to old bnprep;
// recomputed redundantly per block -> kills the 1-block bnprep launches)
__device__ __forceinline__ void bnprep_to_lds(
    const float* __restrict__ in_sums, const float* __restrict__ in_sumsq,
    const float* __restrict__ g, const float* __restrict__ be,
    float* sc_s, float* sh_s, int t) {
  if (t < 256) {
    float s = 0.0f, q = 0.0f;
    for (int k = 0; k < 8; ++k) { s += in_sums[k*256 + t]; q += in_sumsq[k*256 + t]; }
    const float inv_n = 1.0f / 65536.0f;
    float mean = s * inv_n;
    float var = q * inv_n - mean*mean;  // biased var, matches jnp.var
    float a = g[t] * rsqrtf(var + 1e-5f);
    sc_s[t] = a;
    sh_s[t] = be[t] - mean * a;
  }
}

// branchless insert of (d,s) into sorted top-3; strict < keeps earlier entries on ties
__device__ __forceinline__ void ins3(float& d0, float& d1, float& d2,
                                     int& i0, int& i1, int& i2, float d, int s) {
  bool c0 = d < d0, c1 = d < d1, c2 = d < d2;
  d2 = c1 ? d1 : (c2 ? d : d2);
  i2 = c1 ? i1 : (c2 ? s : i2);
  d1 = c0 ? d0 : (c1 ? d : d1);
  i1 = c0 ? i0 : (c1 ? s : i1);
  d0 = c0 ? d : d0;
  i0 = c0 ? s : i0;
}

// ---------------- 3-NN + inverse-distance weights (fp32 in) ----------------
// grid (N/64, B), block 256. 8 threads per query; each thread scans its
// 128-candidate region for TWO queries (n, n+32) -> each ds_read_b128 is
// amortized over 2 queries (LDS pipe was the binding constraint).
// LDS: 8 staggered regions, stride 516 floats -> conflict-free b128 reads.
// Scan metric d' = |c|^2 - 2*p.c (per-query constant r1 folded out).
__global__ __launch_bounds__(256, 8) void nn3_kernel(
    const float* __restrict__ xyz1, const float* __restrict__ xyz2,
    int* __restrict__ idx_out, float* __restrict__ w_out) {
  __shared__ __align__(16) float cand[8 * 516];  // 16512 B
  const int b = blockIdx.y;
  const int t = threadIdx.x;
  const float* x2 = xyz2 + b * 3072;
  for (int i = t; i < 1024; i += 256) {
    float x = x2[i], y = x2[1024 + i], z = x2[2048 + i];
    f32x4 v = { -2.0f * x, -2.0f * y, -2.0f * z, x*x + y*y + z*z };
    *(f32x4*)&cand[(i >> 7) * 516 + (i & 127) * 4] = v;
  }
  __syncthreads();
  const int q = t >> 3, sub = t & 7;
  const int nA = blockIdx.x * 64 + q;      // query A
  const int nB = nA + 32;                  // query B
  const float* x1 = xyz1 + b * 12288;
  const float pxA = x1[nA], pyA = x1[4096 + nA], pzA = x1[8192 + nA];
  const float pxB = x1[nB], pyB = x1[4096 + nB], pzB = x1[8192 + nB];
  float dA0 = 1e30f, dA1 = 1e30f, dA2 = 1e30f;
  float dB0 = 1e30f, dB1 = 1e30f, dB2 = 1e30f;
  int iA0 = 0, iA1 = 0, iA2 = 0, iB0 = 0, iB1 = 0, iB2 = 0;
  const int sbeg = sub << 7;
  const float* reg = &cand[sub * 516];
  #pragma unroll 2
  for (int ii = 0; ii < 128; ++ii) {
    f32x4 c = *(const f32x4*)(reg + ii * 4);
    float dA = __builtin_fmaf(pxA, c[0],
               __builtin_fmaf(pyA, c[1],
               __builtin_fmaf(pzA, c[2], c[3])));
    float dB = __builtin_fmaf(pxB, c[0],
               __builtin_fmaf(pyB, c[1],
               __builtin_fmaf(pzB, c[2], c[3])));
    ins3(dA0, dA1, dA2, iA0, iA1, iA2, dA, sbeg + ii);
    ins3(dB0, dB1, dB2, iB0, iB1, iB2, dB, sbeg + ii);
  }
  // merge 8 partial lists per query, butterfly; a-list is always the
  // lower-index range on sub==0's tree -> ties keep earlier scan index.
  for (int st = 1; st <= 4; st <<= 1) {
    float e0 = __shfl_xor(dA0, st), e1 = __shfl_xor(dA1, st), e2 = __shfl_xor(dA2, st);
    int   j0 = __shfl_xor(iA0, st), j1 = __shfl_xor(iA1, st), j2 = __shfl_xor(iA2, st);
    ins3(dA0, dA1, dA2, iA0, iA1, iA2, e0, j0);
    ins3(dA0, dA1, dA2, iA0, iA1, iA2, e1, j1);
    ins3(dA0, dA1, dA2, iA0, iA1, iA2, e2, j2);
    float g0 = __shfl_xor(dB0, st), g1 = __shfl_xor(dB1, st), g2 = __shfl_xor(dB2, st);
    int   k0 = __shfl_xor(iB0, st), k1 = __shfl_xor(iB1, st), k2 = __shfl_xor(iB2, st);
    ins3(dB0, dB1, dB2, iB0, iB1, iB2, g0, k0);
    ins3(dB0, dB1, dB2, iB0, iB1, iB2, g1, k1);
    ins3(dB0, dB1, dB2, iB0, iB1, iB2, g2, k2);
  }
  if (sub == 0) {
    {
      const float r1 = pxA*pxA + pyA*pyA + pzA*pzA;
      float w0 = 1.0f/(dA0 + r1 + 1e-8f), w1 = 1.0f/(dA1 + r1 + 1e-8f), w2 = 1.0f/(dA2 + r1 + 1e-8f);
      float inv = 1.0f/(w0 + w1 + w2);
      const int pos = b * 4096 + nA;
      idx_out[pos*3+0] = iA0; idx_out[pos*3+1] = iA1; idx_out[pos*3+2] = iA2;
      w_out[pos*3+0] = w0*inv; w_out[pos*3+1] = w1*inv; w_out[pos*3+2] = w2*inv;
    }
    {
      const float r1 = pxB*pxB + pyB*pyB + pzB*pzB;
      float w0 = 1.0f/(dB0 + r1 + 1e-8f), w1 = 1.0f/(dB1 + r1 + 1e-8f), w2 = 1.0f/(dB2 + r1 + 1e-8f);
      float inv = 1.0f/(w0 + w1 + w2);
      const int pos = b * 4096 + nB;
      idx_out[pos*3+0] = iB0; idx_out[pos*3+1] = iB1; idx_out[pos*3+2] = iB2;
      w_out[pos*3+0] = w0*inv; w_out[pos*3+1] = w1*inv; w_out[pos*3+2] = w2*inv;
    }
  }
}

// ---------------- merged [C=256][L] fp32 -> [L][C] bf16 transposes ----------------
// One launch for both tensors: grid (80, 4, 16), block 256.
// x<64: points1 (L=4096, rstride=512) -> A1; x in [64,80): points2 (L=1024,
// rstride=256) -> p2t. Config select is block-uniform (no divergence).
// Vectorized (r11: scalar read + ushort2 write ran at 2x the traffic floor):
// float4 global reads (16 B/lane), ushort4 global writes (8 B/lane).
// LDS tile is [n][c]-major, row 68 u16 (136 B) so ushort4 LDS reads stay
// 8B-aligned; the transpose stride falls on the scalar LDS-write side
// (~8-way conflict ~3cy/instr, negligible vs global traffic).
__global__ __launch_bounds__(256) void transpose2_cl(
    const float* __restrict__ in1, u16* __restrict__ out1,
    const float* __restrict__ in2, u16* __restrict__ out2) {
  __shared__ u16 tile[64][68];   // [n - n0][c - c0]
  const int bx = blockIdx.x, b = blockIdx.z;
  const float* in; u16* out; int L, rstride, n0;
  if (bx < 64) { in = in1; out = out1; L = 4096; rstride = 512; n0 = bx * 64; }
  else         { in = in2; out = out2; L = 1024; rstride = 256; n0 = (bx - 64) * 64; }
  in  += (size_t)b * 256 * L;
  out += (size_t)b * L * rstride;
  const int c0 = blockIdx.y * 64;
  const int t = threadIdx.x;
  const int ci = t >> 4;          // 0..15
  const int nb = (t & 15) * 4;    // n offset, multiple of 4
  #pragma unroll
  for (int p = 0; p < 4; ++p) {
    const int cc = p*16 + ci;
    f32x4 v = *(const f32x4*)&in[(size_t)(c0 + cc) * L + n0 + nb];  // 16B coalesced
    tile[nb+0][cc] = f2bf(v[0]);
    tile[nb+1][cc] = f2bf(v[1]);
    tile[nb+2][cc] = f2bf(v[2]);
    tile[nb+3][cc] = f2bf(v[3]);
  }
  __syncthreads();
  #pragma unroll
  for (int p = 0; p < 4; ++p) {
    const int nn = p*16 + ci;
    ushort4 o = *(const ushort4*)&tile[nn][nb];                     // 8B aligned
    *(ushort4*)&out[(size_t)(n0 + nn) * rstride + c0 + nb] = o;     // 8B coalesced
  }
}

// ---------------- fp32 -> bf16 conversion for both weight tensors ----------------
// grid 768: first 512 blocks convert w0 (131072), rest convert w1 (65536).
__global__ __launch_bounds__(256) void cvt2_kernel(
    const float* __restrict__ a, u16* __restrict__ oa, int na,
    const float* __restrict__ b2, u16* __restrict__ ob, int nb) {
  int i = blockIdx.x * 256 + threadIdx.x;
  if (i < na) { oa[i] = f2bf(a[i]); }
  else { int j = i - na; if (j < nb) ob[j] = f2bf(b2[j]); }
}

// ---------------- 3-NN feature interpolation into A1 cols 256..511 ----------------
// grid 1024, block 256: 8 lane-groups of 32, each group does one position with
// ushort8 (16B) gathers; 8 iterations -> 64 positions per block.
__global__ __launch_bounds__(256) void interp_kernel(
    const u16* __restrict__ p2t, const int* __restrict__ idx,
    const float* __restrict__ wgt, u16* __restrict__ A1) {
  const int t = threadIdx.x;
  const int ln = t & 31, grp = t >> 5;
  const int c0 = ln * 8;
  for (int i = 0; i < 8; ++i) {
    const int pos = blockIdx.x * 64 + i * 8 + grp;
    const int b = pos >> 12;
    const int j0 = idx[pos*3+0], j1 = idx[pos*3+1], j2 = idx[pos*3+2];
    const float w0 = wgt[pos*3+0], w1 = wgt[pos*3+1], w2 = wgt[pos*3+2];
    ushort8 v0 = *(const ushort8*)(p2t + ((size_t)(b*1024 + j0)) * 256 + c0);
    ushort8 v1 = *(const ushort8*)(p2t + ((size_t)(b*1024 + j1)) * 256 + c0);
    ushort8 v2 = *(const ushort8*)(p2t + ((size_t)(b*1024 + j2)) * 256 + c0);
    ushort8 o;
    #pragma unroll
    for (int j = 0; j < 8; ++j)
      o[j] = f2bf(w0*bf2f(v0[j]) + w1*bf2f(v1[j]) + w2*bf2f(v2[j]));
    *(ushort8*)(A1 + (size_t)pos*512 + 256 + c0) = o;
  }
}

// ---------------- bf16 GEMM + fused per-channel stats (+optional fused BN) ----
// Y[m][n] = sum_k Ain[m][k]*Bw[n][k] + bias[n], where Ain = A (FUSE=0) or
// Ain = relu(A*scale[k]+shift[k]) with scale/shift computed IN-KERNEL from the
// previous layer's banked sums (identical math to old bnprep; deterministic,
// so every block computes the same values -> no separate launch needed).
// grid (M/128, N/128), block 256 (4 waves, 2x2 of 64x64 per wave).
// K-loop: round-1 compiler-scheduled structure (reg-staged, 2 barriers/step;
// manual pipelines all regressed r3-r5), BK=64 (r8: 46->41 us).
// LDS row stride 72 u16 = 144 B: uniform 8 lanes/16B window on both sides.
// Stats out: wave shfl-reduce -> LDS atomic (dead As reuse) -> one global
// atomic per col per block into 8-way banked sums[8][256] (r6/r7 lesson).
template <int FUSE>
__global__ __launch_bounds__(256) void gemm_kernel(
    const u16* __restrict__ A, const u16* __restrict__ Bw,
    const float* __restrict__ bias, u16* __restrict__ Y, int K,
    float* __restrict__ sums, float* __restrict__ sumsq,
    const float* __restrict__ in_sums, const float* __restrict__ in_sumsq,
    const float* __restrict__ g, const float* __restrict__ be) {
  __shared__ __align__(16) u16 As[128*72];
  __shared__ __align__(16) u16 Bs[128*72];
  __shared__ float sc_s[256], sh_s[256];
  const int t = threadIdx.x;
  const int m0 = blockIdx.x * 128, n0 = blockIdx.y * 128;
  const int wave = t >> 6, l = t & 63;
  const int wm = wave & 1, wn = wave >> 1;
  const int lc = l & 15, quad = l >> 4;
  f32x4 acc[4][4] = {};
  const int r = t >> 3, kc = (t & 7) * 8;   // staging: 8 threads/row, 16B each
  if (FUSE) {
    bnprep_to_lds(in_sums, in_sumsq, g, be, sc_s, sh_s, t);
    __syncthreads();
  }
  for (int k0 = 0; k0 < K; k0 += 64) {
    f32x4 sc_lo, sc_hi, sh_lo, sh_hi;
    if (FUSE) {
      sc_lo = *(const f32x4*)&sc_s[k0 + kc];
      sc_hi = *(const f32x4*)&sc_s[k0 + kc + 4];
      sh_lo = *(const f32x4*)&sh_s[k0 + kc];
      sh_hi = *(const f32x4*)&sh_s[k0 + kc + 4];
    }
    #pragma unroll
    for (int p = 0; p < 4; ++p) {
      const int row = p*32 + r;
      u32x4 va = *(const u32x4*)&A [(size_t)(m0 + row)*K + k0 + kc];
      u32x4 vb = *(const u32x4*)&Bw[(size_t)(n0 + row)*K + k0 + kc];
      if (FUSE) {
        va[0] = bn2(va[0], sc_lo[0], sh_lo[0], sc_lo[1], sh_lo[1]);
        va[1] = bn2(va[1], sc_lo[2], sh_lo[2], sc_lo[3], sh_lo[3]);
        va[2] = bn2(va[2], sc_hi[0], sh_hi[0], sc_hi[1], sh_hi[1]);
        va[3] = bn2(va[3], sc_hi[2], sh_hi[2], sc_hi[3], sh_hi[3]);
      }
      *(u32x4*)&As[row*72 + kc] = va;
      *(u32x4*)&Bs[row*72 + kc] = vb;
    }
    __syncthreads();
    #pragma unroll
    for (int h = 0; h < 2; ++h) {
      short8 af[4], bfv[4];
      for (int tm = 0; tm < 4; ++tm)
        af[tm] = *(const short8*)&As[(wm*64 + tm*16 + lc)*72 + h*32 + quad*8];
      for (int tn = 0; tn < 4; ++tn)
        bfv[tn] = *(const short8*)&Bs[(wn*64 + tn*16 + lc)*72 + h*32 + quad*8];
      for (int tm = 0; tm < 4; ++tm)
        for (int tn = 0; tn < 4; ++tn)
          acc[tm][tn] = __builtin_amdgcn_mfma_f32_16x16x32_bf16(af[tm], bfv[tn], acc[tm][tn], 0, 0, 0);
    }
    __syncthreads();
  }
  // As is dead now -> reuse 1 KiB as the block's stats scratch.
  float* sl = (float*)As;            // sl[0..127]=sum per block-col, sl[128..255]=sumsq
  if (t < 256) sl[t] = 0.0f;
  __syncthreads();
  for (int tn = 0; tn < 4; ++tn) {
    const int colL = wn*64 + tn*16 + lc;          // col within block [0,128)
    const float bb = bias[n0 + colL];
    float s = 0.0f, q = 0.0f;
    for (int tm = 0; tm < 4; ++tm) {
      const int row = m0 + wm*64 + tm*16 + quad*4;
      for (int rr = 0; rr < 4; ++rr) {
        float v = acc[tm][tn][rr] + bb;           // C/D: col=lane&15, row=quad*4+reg
        Y[(size_t)(row + rr)*256 + n0 + colL] = f2bf(v);
        s += v; q += v*v;
      }
    }
    // reduce the 4 quads holding this col, then LDS-atomic (2 waves/addr)
    s += __shfl_xor(s, 16); s += __shfl_xor(s, 32);
    q += __shfl_xor(q, 16); q += __shfl_xor(q, 32);
    if (quad == 0) {
      atomicAdd(&sl[colL], s);
      atomicAdd(&sl[128 + colL], q);
    }
  }
  __syncthreads();
  if (t < 128) {                     // one global atomic per col per block, 8-banked
    const int bank = (blockIdx.x & 7) * 256;
    atomicAdd(&sums [bank + n0 + t], sl[t]);
    atomicAdd(&sumsq[bank + n0 + t], sl[128 + t]);
  }
}

// ---------------- BN+ReLU + transpose to [b][c][n] fp32 output ----------------
// grid (64, 1, 16), block 256. scale/shift computed in-kernel from banked sums
// (kills the second bnprep launch). Vectorized ushort4 reads; ds_write_b64
// into [n][c] tile (stride 266 -> conflict-free u32 reads in phase 2).
__global__ __launch_bounds__(256) void bnrelu_tr_kernel(
    const u16* __restrict__ Y,
    const float* __restrict__ in_sums, const float* __restrict__ in_sumsq,
    const float* __restrict__ g, const float* __restrict__ be,
    float* __restrict__ out) {
  __shared__ u16 tile[64][266];   // [n - n0][channel]
  __shared__ float sc_s[256], sh_s[256];
  const int t = threadIdx.x;
  const int b = blockIdx.z;
  const int n0 = blockIdx.x * 64;
  bnprep_to_lds(in_sums, in_sumsq, g, be, sc_s, sh_s, t);
  __syncthreads();
  const int ln = t & 63, grp = t >> 6;
  const int c0 = ln * 4;
  const f32x4 a4 = *(const f32x4*)&sc_s[c0];
  const f32x4 s4 = *(const f32x4*)&sh_s[c0];
  for (int it = 0; it < 16; ++it) {
    const int nn = it*4 + grp;
    size_t pos = (size_t)b*4096 + n0 + nn;
    ushort4 v = *(const ushort4*)&Y[pos*256 + c0];
    ushort4 o;
    float f0 = bf2f(v.x)*a4[0] + s4[0];
    float f1 = bf2f(v.y)*a4[1] + s4[1];
    float f2v = bf2f(v.z)*a4[2] + s4[2];
    float f3 = bf2f(v.w)*a4[3] + s4[3];
    o.x = f2bf(f0 > 0.0f ? f0 : 0.0f);
    o.y = f2bf(f1 > 0.0f ? f1 : 0.0f);
    o.z = f2bf(f2v > 0.0f ? f2v : 0.0f);
    o.w = f2bf(f3 > 0.0f ? f3 : 0.0f);
    *(ushort4*)&tile[nn][c0] = o;   // ds_write_b64
  }
  __syncthreads();
  // phase 2: lane = n index; each iteration covers 2 channels via one u32 read
  for (int p = 0; p < 32; ++p) {
    const int oo = p*8 + grp*2;
    ushort2 v = *(const ushort2*)&tile[ln][oo];   // u32 LDS read, conflict-free
    out[((size_t)b*256 + oo    )*4096 + n0 + ln] = bf2f(v.x);
    out[((size_t)b*256 + oo + 1)*4096 + n0 + ln] = bf2f(v.y);
  }
}

extern "C" void kernel_launch(void* const* d_in, const int* in_sizes, int n_in,
                              void* d_out, int out_size, void* d_ws, size_t ws_size,
                              hipStream_t stream) {
  const float* xyz1    = (const float*)d_in[0];
  const float* xyz2    = (const float*)d_in[1];
  const float* points1 = (const float*)d_in[2];
  const float* points2 = (const float*)d_in[3];
  const float* w0      = (const float*)d_in[4];
  const float* b0      = (const float*)d_in[5];
  const float* g0      = (const float*)d_in[6];
  const float* be0     = (const float*)d_in[7];
  const float* w1      = (const float*)d_in[8];
  const float* b1      = (const float*)d_in[9];
  const float* g1      = (const float*)d_in[10];
  const float* be1     = (const float*)d_in[11];
  float* out = (float*)d_out;

  // ---- workspace layout (~107 MiB used) ----
  char* ws = (char*)d_ws;
  u16*   A1   = (u16*)ws;                          // [65536][512] bf16, 64 MiB (dead after gemm1)
  u16*   Y2   = (u16*)ws;                          // [65536][256] bf16, 32 MiB (overlays dead A1)
  u16*   Y    = (u16*)(ws + (64ull  << 20));       // [65536][256] bf16, 32 MiB
  u16*   p2t  = (u16*)(ws + (96ull  << 20));       // [16*1024][256] bf16, 8 MiB
  int*   idxb = (int*)(ws + (104ull << 20));       // 768 KiB
  float* wgtb = (float*)(ws + (105ull << 20));     // 768 KiB
  u16*   w0b  = (u16*)(ws + (106ull << 20));       // [256][512] bf16, 256 KiB
  u16*   w1b  = (u16*)(ws + (106ull << 20) + (256u << 10)); // [256][256] bf16, 128 KiB
  float* stats= (float*)(ws + (106ull << 20) + (512u << 10)); // 8192 floats

  // banked accumulators [8][256] each
  float* sums0  = stats;          // 2048
  float* sumsq0 = stats + 2048;   // 2048
  float* sums1  = stats + 4096;   // 2048
  float* sumsq1 = stats + 6144;   // 2048

  hipMemsetAsync(stats, 0, 8192 * sizeof(float), stream);
  nn3_kernel<<<dim3(64, 16), 256, 0, stream>>>(xyz1, xyz2, idxb, wgtb);
  transpose2_cl<<<dim3(80, 4, 16), 256, 0, stream>>>(points1, A1, points2, p2t);
  cvt2_kernel<<<768, 256, 0, stream>>>(w0, w0b, 131072, w1, w1b, 65536);
  interp_kernel<<<1024, 256, 0, stream>>>(p2t, idxb, wgtb, A1);
  gemm_kernel<0><<<dim3(512, 2), 256, 0, stream>>>(A1, w0b, b0, Y, 512, sums0, sumsq0,
                                                   nullptr, nullptr, nullptr, nullptr);
  gemm_kernel<1><<<dim3(512, 2), 256, 0, stream>>>(Y, w1b, b1, Y2, 256, sums1, sumsq1,
                                                   sums0, sumsq0, g0, be0);
  bnrelu_tr_kernel<<<dim3(64, 1, 16), 256, 0, stream>>>(Y2, sums1, sumsq1, g1, be1, out);
}